// Round 11
// baseline (59.727 us; speedup 1.0000x reference)
//
#include <hip/hip_runtime.h>
#include <stdint.h>

// YOLOv3 head decode: B=32, NA=3 anchors, 76x76 grid, 85 attrs, stride=8.
// in : [B, 255, 76, 76] f32   (c-major, spatial contiguous)
// out: [B, 3*76*76, 85] f32   (attr contiguous)
//
// BARRIER-FREE wave-autonomous transpose, TWO units per wave.
// Unit = (row, 4-column group); wave handles units {ubase, ubase+1} (adjacent:
// same 64B input line per lane 90% of the time -> L1 hit, L2 requests halved;
// 4 dwordx4 loads in flight per wave).
//   load   : lane c: global_load_dwordx4 inb+c*SPATIAL per unit
//   xform  : registers (channel uniform per lane; fine-grained vmcnt)
//   scatter: LDS outbuf[s][t*85+c], lanes consecutive -> conflict-free
//   wait   : s_waitcnt lgkmcnt(0)   (wave-local; no __syncthreads anywhere)
//   store  : contiguous NT dwordx4 (2 x 1360 B per wave, usually adjacent)
// LDS = 2.72 KB/wave -> 10.9 KB/block (256 thr) -> 8 blocks/CU.

#define GH 76
#define GW 76
#define NA 3
#define ATTRS 85
#define SPATIAL (GH * GW)          // 5776
#define NGRP 19                    // 76/4 column groups per row
#define LOG2E 1.4426950408889634f

typedef float f32x4 __attribute__((ext_vector_type(4)));

__global__ __launch_bounds__(256) void yolo_head_kernel(
    const float* __restrict__ in, float* __restrict__ out, int nwg) {
    // ---- bijective XCD swizzle (nwg % 8 == 0 here) ----
    const int L = blockIdx.x;
    const int q = nwg >> 3, r = nwg & 7, xcd = L & 7;
    const int W = (xcd < r ? xcd * (q + 1) : r * (q + 1) + (xcd - r) * q) + (L >> 3);

    const int lane = threadIdx.x & 63;
    const int wv   = threadIdx.x >> 6;

    const int ubase = W * 8 + wv * 2;      // this wave's 2 adjacent units

    __shared__ float outbuf_all[4][2 * ATTRS * 4];   // 2.72 KB per wave
    float* outbuf = outbuf_all[wv];

    // per-unit geometry (computed for both units; s,k all compile-time unrolled)
    int row_[2], g_[2], gy_[2];
    float aw_[2], ah_[2];
    const float* inb_[2];
#pragma unroll
    for (int s = 0; s < 2; ++s) {
        const int u   = ubase + s;
        const int row = u / NGRP;
        const int g   = u - row * NGRP;
        const int gy  = row % GH;
        const int t2  = row / GH;
        const int a   = t2 % NA;
        const int b   = t2 / NA;
        row_[s] = row; g_[s] = g; gy_[s] = gy;
        aw_[s] = (a == 0) ? 10.0f : (a == 1) ? 16.0f : 33.0f;
        ah_[s] = (a == 0) ? 13.0f : (a == 1) ? 30.0f : 23.0f;
        inb_[s] = in + ((size_t)(b * (NA * ATTRS) + a * ATTRS)) * SPATIAL
                     + (size_t)gy * GW + g * 4;
    }

    // ---- loads first: 4 independent dwordx4 per lane in flight ----
    f32x4 v[2][2];
#pragma unroll
    for (int s = 0; s < 2; ++s)
#pragma unroll
        for (int k = 0; k < 2; ++k) {
            const int c = lane + k * 64;
            if (c < ATTRS)
                v[s][k] = *reinterpret_cast<const f32x4*>(inb_[s] + (size_t)c * SPATIAL);
        }

    // ---- transform (channel uniform per lane) + scatter to LDS ----
#pragma unroll
    for (int s = 0; s < 2; ++s)
#pragma unroll
        for (int k = 0; k < 2; ++k) {
            const int c = lane + k * 64;
            if (c < ATTRS) {
                f32x4 E, rs;
#pragma unroll
                for (int t = 0; t < 4; ++t) {
                    E[t]  = __builtin_amdgcn_exp2f(LOG2E * v[s][k][t]);   // e^x
                    rs[t] = E[t] * __builtin_amdgcn_rcpf(1.0f + E[t]);    // sigmoid
                }
                if (c < 4) {
                    const float gx0 = (float)(g_[s] * 4);
#pragma unroll
                    for (int t = 0; t < 4; ++t) {
                        if      (c == 0) rs[t] = (rs[t] + gx0 + (float)t) * 8.0f;
                        else if (c == 1) rs[t] = (rs[t] + (float)gy_[s]) * 8.0f;
                        else if (c == 2) rs[t] = E[t] * aw_[s];
                        else              rs[t] = E[t] * ah_[s];
                    }
                }
#pragma unroll
                for (int t = 0; t < 4; ++t)
                    outbuf[s * (ATTRS * 4) + t * ATTRS + c] = rs[t];  // conflict-free
            }
        }
    asm volatile("s_waitcnt lgkmcnt(0)" ::: "memory");  // wave-local wait

    // ---- store: contiguous NT dwordx4 stream (2 x 1360 B, usually adjacent) ----
#pragma unroll
    for (int s = 0; s < 2; ++s) {
        float* outg = out + (size_t)row_[s] * (GW * ATTRS) + g_[s] * (4 * ATTRS);
#pragma unroll
        for (int k = 0; k < 2; ++k) {
            const int j = lane + k * 64;
            if (j < ATTRS) {
                const f32x4 sv = *reinterpret_cast<const f32x4*>(
                    &outbuf[s * (ATTRS * 4) + j * 4]);
                __builtin_nontemporal_store(sv, reinterpret_cast<f32x4*>(outg + j * 4));
            }
        }
    }
}

extern "C" void kernel_launch(void* const* d_in, const int* in_sizes, int n_in,
                              void* d_out, int out_size, void* d_ws, size_t ws_size,
                              hipStream_t stream) {
    const float* in = (const float*)d_in[0];
    float* out = (float*)d_out;
    const int B = in_sizes[0] / (NA * ATTRS * SPATIAL);  // 32
    const int nunits = GH * NA * B * NGRP;               // 138624
    const int nwg = nunits / 8;                          // 17328 (div by 8)
    yolo_head_kernel<<<dim3(nwg), 256, 0, stream>>>(in, out, nwg);
}